// Round 4
// baseline (112.533 us; speedup 1.0000x reference)
//
#include <hip/hip_runtime.h>

#define NHEADS 6
#define HD 32
#define CDIM 192
#define NTOK 64
#define NREL 225
#define PDIM 12
#define IMG 256
#define NWW 32
#define NWIN 2048
#define SCALE 0.17677669529663687f

typedef __attribute__((ext_vector_type(8))) short v8s;
typedef __attribute__((ext_vector_type(4))) float v4f;

#define VTS 72   // vt row stride bf16 (144B, 16B-multiple for b128 reads)
#define PTS 72   // pt row stride bf16

__device__ __forceinline__ unsigned short f2bf(float f) {
    union { float f; unsigned u; } c; c.f = f;
    unsigned u = c.u + 0x7fffu + ((c.u >> 16) & 1u);
    return (unsigned short)(u >> 16);
}

__device__ __forceinline__ void ln_relu12(const float* x, const float* g,
                                          const float* be, float* y) {
    float m = 0.f;
#pragma unroll
    for (int i = 0; i < PDIM; ++i) m += x[i];
    m *= (1.f / PDIM);
    float v = 0.f;
#pragma unroll
    for (int i = 0; i < PDIM; ++i) { float d = x[i] - m; v += d * d; }
    v *= (1.f / PDIM);
    float inv = rsqrtf(v + 1e-5f);
#pragma unroll
    for (int i = 0; i < PDIM; ++i) {
        float t = (x[i] - m) * inv * g[i] + be[i];
        y[i] = t > 0.f ? t : 0.f;
    }
}

// grid=96; each block recomputes the tiny MLP then writes its 256-elem slice
__global__ __launch_bounds__(256) void posbias_kernel(
    const float* __restrict__ wp, const float* __restrict__ bp,
    const float* __restrict__ g1, const float* __restrict__ be1,
    const float* __restrict__ w1, const float* __restrict__ b1,
    const float* __restrict__ g2, const float* __restrict__ be2,
    const float* __restrict__ w2, const float* __restrict__ b2,
    const float* __restrict__ g3, const float* __restrict__ be3,
    const float* __restrict__ w3, const float* __restrict__ b3,
    float* __restrict__ rpb)
{
    __shared__ float p_sh[NREL * NHEADS];
    int r = threadIdx.x;
    if (r < NREL) {
        float x0 = (float)(r / 15 - 7);
        float x1 = (float)(r % 15 - 7);
        float h[PDIM], y[PDIM];
#pragma unroll
        for (int o = 0; o < PDIM; ++o)
            h[o] = x0 * wp[o] + x1 * wp[PDIM + o] + bp[o];
        ln_relu12(h, g1, be1, y);
#pragma unroll
        for (int o = 0; o < PDIM; ++o) {
            float a = b1[o];
#pragma unroll
            for (int i = 0; i < PDIM; ++i) a += y[i] * w1[i * PDIM + o];
            h[o] = a;
        }
        ln_relu12(h, g2, be2, y);
#pragma unroll
        for (int o = 0; o < PDIM; ++o) {
            float a = b2[o];
#pragma unroll
            for (int i = 0; i < PDIM; ++i) a += y[i] * w2[i * PDIM + o];
            h[o] = a;
        }
        ln_relu12(h, g3, be3, y);
#pragma unroll
        for (int o = 0; o < NHEADS; ++o) {
            float a = b3[o];
#pragma unroll
            for (int i = 0; i < PDIM; ++i) a += y[i] * w3[i * NHEADS + o];
            p_sh[r * NHEADS + o] = a;
        }
    }
    __syncthreads();
    int i = blockIdx.x * 256 + threadIdx.x;
    int h = i >> 12;
    int n = (i >> 6) & 63;
    int m = i & 63;
    int idx = ((n >> 3) - (m >> 3) + 7) * 15 + ((n & 7) - (m & 7) + 7);
    rpb[i] = p_sh[idx * NHEADS + h];
}

__global__ __launch_bounds__(256, 8) void win_attn_mfma(
    const float* __restrict__ qkv, const float* __restrict__ rpb,
    float* __restrict__ out)
{
    __shared__ unsigned short vt[HD * VTS];    // V transposed (d-major)
    __shared__ unsigned short pt[NTOK * PTS];  // P bf16

    const int t = threadIdx.x;
    const int head = blockIdx.x >> 11;          // head-major: rpb tile reuse
    const int win  = blockIdx.x & (NWIN - 1);
    const int b    = win >> 10;
    const int bh   = (win >> 5) & 31;
    const int bw   = win & 31;

    const int lane = t & 63;
    const int wave = t >> 6;
    const int lw = lane & 15;
    const int lg = lane >> 4;
    const int rowbase = wave * 16;

    const size_t SST = (size_t)2 * IMG * IMG * CDIM;
    const float* basep = qkv + (size_t)b * IMG * IMG * CDIM + head * HD;

    // token -> float offset of its pixel
    auto toff = [&](int tok) -> size_t {
        return ((size_t)(bh * 8 + (tok >> 3)) * IMG + (bw * 8 + (tok & 7))) * CDIM;
    };

    // ---- stage V only (transposed bf16); no barrier yet ----
#pragma unroll
    for (int pass = 0; pass < 2; ++pass) {
        int idx = t + pass * 256;
        int tok = idx >> 3;
        int d   = (idx & 7) * 4;
        float4 v4 = *(const float4*)(basep + 2 * SST + toff(tok) + d);
        vt[(d + 0) * VTS + tok] = f2bf(v4.x);
        vt[(d + 1) * VTS + tok] = f2bf(v4.y);
        vt[(d + 2) * VTS + tok] = f2bf(v4.z);
        vt[(d + 3) * VTS + tok] = f2bf(v4.w);
    }

    // ---- Q A-fragment direct from global (8 consecutive d of one token) ----
    v8s a;
    {
        const float* qp = basep + toff(rowbase + lw) + lg * 8;
        float4 q0 = *(const float4*)qp;
        float4 q1 = *(const float4*)(qp + 4);
        a[0] = (short)f2bf(q0.x * SCALE); a[1] = (short)f2bf(q0.y * SCALE);
        a[2] = (short)f2bf(q0.z * SCALE); a[3] = (short)f2bf(q0.w * SCALE);
        a[4] = (short)f2bf(q1.x * SCALE); a[5] = (short)f2bf(q1.y * SCALE);
        a[6] = (short)f2bf(q1.z * SCALE); a[7] = (short)f2bf(q1.w * SCALE);
    }

    // ---- S = Q K^T + rpb; K B-fragments direct from global (L1-hot) ----
    v4f acc[4];
    {
        const float* rpbh = rpb + head * NTOK * NTOK
                          + (rowbase + lg * 4) * NTOK + lw;
#pragma unroll
        for (int ct = 0; ct < 4; ++ct) {
            const float* kp = basep + SST + toff(ct * 16 + lw) + lg * 8;
            float4 k0 = *(const float4*)kp;
            float4 k1 = *(const float4*)(kp + 4);
            v8s bfr;
            bfr[0] = (short)f2bf(k0.x); bfr[1] = (short)f2bf(k0.y);
            bfr[2] = (short)f2bf(k0.z); bfr[3] = (short)f2bf(k0.w);
            bfr[4] = (short)f2bf(k1.x); bfr[5] = (short)f2bf(k1.y);
            bfr[6] = (short)f2bf(k1.z); bfr[7] = (short)f2bf(k1.w);
#pragma unroll
            for (int r = 0; r < 4; ++r)
                acc[ct][r] = rpbh[r * NTOK + ct * 16];
            acc[ct] = __builtin_amdgcn_mfma_f32_16x16x32_bf16(a, bfr, acc[ct], 0, 0, 0);
        }
    }

    // ---- softmax fully in-register ----
    {
        v4f mx4;
#pragma unroll
        for (int r = 0; r < 4; ++r)
            mx4[r] = fmaxf(fmaxf(acc[0][r], acc[1][r]), fmaxf(acc[2][r], acc[3][r]));
#pragma unroll
        for (int off = 1; off < 16; off <<= 1)
#pragma unroll
            for (int r = 0; r < 4; ++r)
                mx4[r] = fmaxf(mx4[r], __shfl_xor(mx4[r], off));
        v4f s4 = {0.f, 0.f, 0.f, 0.f};
#pragma unroll
        for (int ct = 0; ct < 4; ++ct)
#pragma unroll
            for (int r = 0; r < 4; ++r) {
                acc[ct][r] = __expf(acc[ct][r] - mx4[r]);
                s4[r] += acc[ct][r];
            }
#pragma unroll
        for (int off = 1; off < 16; off <<= 1)
#pragma unroll
            for (int r = 0; r < 4; ++r)
                s4[r] += __shfl_xor(s4[r], off);
        v4f rinv;
#pragma unroll
        for (int r = 0; r < 4; ++r) rinv[r] = 1.f / s4[r];
#pragma unroll
        for (int ct = 0; ct < 4; ++ct)
#pragma unroll
            for (int r = 0; r < 4; ++r)
                pt[(rowbase + lg * 4 + r) * PTS + ct * 16 + lw] =
                    f2bf(acc[ct][r] * rinv[r]);
    }
    __syncthreads();   // vt (cross-wave) + pt visibility before PV

    // ---- O = P V ----
    {
        v8s pa[2];
#pragma unroll
        for (int kt = 0; kt < 2; ++kt)
            pa[kt] = *(const v8s*)&pt[(rowbase + lw) * PTS + kt * 32 + lg * 8];
        v4f acc2[2] = {};
#pragma unroll
        for (int dt = 0; dt < 2; ++dt)
#pragma unroll
            for (int kt = 0; kt < 2; ++kt) {
                v8s vb = *(const v8s*)&vt[(dt * 16 + lw) * VTS + kt * 32 + lg * 8];
                acc2[dt] = __builtin_amdgcn_mfma_f32_16x16x32_bf16(pa[kt], vb, acc2[dt], 0, 0, 0);
            }
#pragma unroll
        for (int dt = 0; dt < 2; ++dt)
#pragma unroll
            for (int r = 0; r < 4; ++r) {
                int n = rowbase + lg * 4 + r;
                size_t off = (((size_t)b * IMG + bh * 8 + (n >> 3)) * IMG
                              + (bw * 8 + (n & 7))) * CDIM + head * HD + dt * 16 + lw;
                out[off] = acc2[dt][r];
            }
    }
}

extern "C" void kernel_launch(void* const* d_in, const int* in_sizes, int n_in,
                              void* d_out, int out_size, void* d_ws, size_t ws_size,
                              hipStream_t stream) {
    const float* qkv = (const float*)d_in[0];
    const float* wp  = (const float*)d_in[1];
    const float* bp  = (const float*)d_in[2];
    const float* g1  = (const float*)d_in[3];
    const float* be1 = (const float*)d_in[4];
    const float* w1  = (const float*)d_in[5];
    const float* b1  = (const float*)d_in[6];
    const float* g2  = (const float*)d_in[7];
    const float* be2 = (const float*)d_in[8];
    const float* w2  = (const float*)d_in[9];
    const float* b2  = (const float*)d_in[10];
    const float* g3  = (const float*)d_in[11];
    const float* be3 = (const float*)d_in[12];
    const float* w3  = (const float*)d_in[13];
    const float* b3  = (const float*)d_in[14];

    float* rpb = (float*)d_ws;  // 6*64*64 floats
    posbias_kernel<<<96, 256, 0, stream>>>(wp, bp, g1, be1, w1, b1,
                                           g2, be2, w2, b2, g3, be3, w3, b3, rpb);
    win_attn_mfma<<<NWIN * NHEADS, 256, 0, stream>>>(qkv, rpb, (float*)d_out);
}

// Round 5
// 99.250 us; speedup vs baseline: 1.1338x; 1.1338x over previous
//
#include <hip/hip_runtime.h>
#include <hip/hip_bf16.h>

#define NHEADS 6
#define HD 32
#define CDIM 192
#define NTOK 64
#define NREL 225
#define PDIM 12
#define IMG 256
#define NWW 32
#define NWIN 2048
#define SCALE 0.17677669529663687f
#define INV_SCALE 5.656854249492381f

typedef __attribute__((ext_vector_type(8))) short v8s;
typedef __attribute__((ext_vector_type(4))) float v4f;

// LDS strides (ushort elements); row byte strides are 16B multiples
#define QKS 40   // ks row stride (80B)
#define VTS 72   // vt row stride (144B)
#define PTS 72   // pt row stride (144B)

// packed 2xf32 -> 2xbf16 (v_cvt_pk_bf16_f32)
__device__ __forceinline__ unsigned pkbf(float x, float y) {
    __hip_bfloat162 h = __float22bfloat162_rn(make_float2(x, y));
    union { __hip_bfloat162 h; unsigned u; } c; c.h = h;
    return c.u;
}
__device__ __forceinline__ unsigned short bf1(float x) {
    __hip_bfloat16 h = __float2bfloat16(x);
    union { __hip_bfloat16 h; unsigned short u; } c; c.h = h;
    return c.u;
}

__device__ __forceinline__ void ln_relu12(const float* x, const float* g,
                                          const float* be, float* y) {
    float m = 0.f;
#pragma unroll
    for (int i = 0; i < PDIM; ++i) m += x[i];
    m *= (1.f / PDIM);
    float v = 0.f;
#pragma unroll
    for (int i = 0; i < PDIM; ++i) { float d = x[i] - m; v += d * d; }
    v *= (1.f / PDIM);
    float inv = rsqrtf(v + 1e-5f);
#pragma unroll
    for (int i = 0; i < PDIM; ++i) {
        float t = (x[i] - m) * inv * g[i] + be[i];
        y[i] = t > 0.f ? t : 0.f;
    }
}

// grid=96; writes rpb pre-divided by SCALE (scale re-applied inside exp)
__global__ __launch_bounds__(256) void posbias_kernel(
    const float* __restrict__ wp, const float* __restrict__ bp,
    const float* __restrict__ g1, const float* __restrict__ be1,
    const float* __restrict__ w1, const float* __restrict__ b1,
    const float* __restrict__ g2, const float* __restrict__ be2,
    const float* __restrict__ w2, const float* __restrict__ b2,
    const float* __restrict__ g3, const float* __restrict__ be3,
    const float* __restrict__ w3, const float* __restrict__ b3,
    float* __restrict__ rpb)
{
    __shared__ float p_sh[NREL * NHEADS];
    int r = threadIdx.x;
    if (r < NREL) {
        float x0 = (float)(r / 15 - 7);
        float x1 = (float)(r % 15 - 7);
        float h[PDIM], y[PDIM];
#pragma unroll
        for (int o = 0; o < PDIM; ++o)
            h[o] = x0 * wp[o] + x1 * wp[PDIM + o] + bp[o];
        ln_relu12(h, g1, be1, y);
#pragma unroll
        for (int o = 0; o < PDIM; ++o) {
            float a = b1[o];
#pragma unroll
            for (int i = 0; i < PDIM; ++i) a += y[i] * w1[i * PDIM + o];
            h[o] = a;
        }
        ln_relu12(h, g2, be2, y);
#pragma unroll
        for (int o = 0; o < PDIM; ++o) {
            float a = b2[o];
#pragma unroll
            for (int i = 0; i < PDIM; ++i) a += y[i] * w2[i * PDIM + o];
            h[o] = a;
        }
        ln_relu12(h, g3, be3, y);
#pragma unroll
        for (int o = 0; o < NHEADS; ++o) {
            float a = b3[o];
#pragma unroll
            for (int i = 0; i < PDIM; ++i) a += y[i] * w3[i * NHEADS + o];
            p_sh[r * NHEADS + o] = a * INV_SCALE;
        }
    }
    __syncthreads();
    int i = blockIdx.x * 256 + threadIdx.x;
    int h = i >> 12;
    int n = (i >> 6) & 63;
    int m = i & 63;
    int idx = ((n >> 3) - (m >> 3) + 7) * 15 + ((n & 7) - (m & 7) + 7);
    rpb[i] = p_sh[idx * NHEADS + h];
}

__global__ __launch_bounds__(256, 8) void win_attn_mfma(
    const float* __restrict__ qkv, const float* __restrict__ rpb,
    float* __restrict__ out)
{
    __shared__ unsigned short ks[NTOK * QKS];  // K row-major bf16
    __shared__ unsigned short vt[HD * VTS];    // V transposed bf16
    __shared__ unsigned short pt[NTOK * PTS];  // P bf16 (wave-private rows)

    const int t = threadIdx.x;
    const int head = blockIdx.x >> 11;          // head-major: rpb tile reuse
    const int win  = blockIdx.x & (NWIN - 1);
    const int b    = win >> 10;
    const int bh   = (win >> 5) & 31;
    const int bw   = win & 31;

    const int lane = t & 63;
    const int wave = t >> 6;
    const int lw = lane & 15;
    const int lg = lane >> 4;
    const int rowbase = wave * 16;

    const size_t SST = (size_t)2 * IMG * IMG * CDIM;
    const float* basep = qkv + (size_t)b * IMG * IMG * CDIM + head * HD;

    auto toff = [&](int tok) -> size_t {
        return ((size_t)(bh * 8 + (tok >> 3)) * IMG + (bw * 8 + (tok & 7))) * CDIM;
    };

    // ---- stage K (row-major) + V (transposed); 2 passes x 2 tensors ----
#pragma unroll
    for (int pass = 0; pass < 2; ++pass) {
        int idx = t + pass * 256;
        int tok = idx >> 3;
        int d   = (idx & 7) * 4;
        const float* kp = basep + SST + toff(tok) + d;
        float4 k4 = *(const float4*)kp;
        float4 v4 = *(const float4*)(kp + SST);
        uint2 kk; kk.x = pkbf(k4.x, k4.y); kk.y = pkbf(k4.z, k4.w);
        *(uint2*)&ks[tok * QKS + d] = kk;
        vt[(d + 0) * VTS + tok] = bf1(v4.x);
        vt[(d + 1) * VTS + tok] = bf1(v4.y);
        vt[(d + 2) * VTS + tok] = bf1(v4.z);
        vt[(d + 3) * VTS + tok] = bf1(v4.w);
    }

    // ---- Q A-fragment direct from global (wave-local rows; pure cvt) ----
    v8s a;
    {
        const float* qp = basep + toff(rowbase + lw) + lg * 8;
        float4 q0 = *(const float4*)qp;
        float4 q1 = *(const float4*)(qp + 4);
        union { v8s v; unsigned u[4]; } au;
        au.u[0] = pkbf(q0.x, q0.y);
        au.u[1] = pkbf(q0.z, q0.w);
        au.u[2] = pkbf(q1.x, q1.y);
        au.u[3] = pkbf(q1.z, q1.w);
        a = au.v;
    }
    __syncthreads();   // ks + vt visible to all waves

    // ---- S' = Q K^T + rpb/SCALE  (C-input = bias) ----
    v4f acc[4];
    {
        const float* rpbh = rpb + head * NTOK * NTOK
                          + (rowbase + lg * 4) * NTOK + lw;
#pragma unroll
        for (int ct = 0; ct < 4; ++ct) {
#pragma unroll
            for (int r = 0; r < 4; ++r)
                acc[ct][r] = rpbh[r * NTOK + ct * 16];
            v8s bfr = *(const v8s*)&ks[(ct * 16 + lw) * QKS + lg * 8];
            acc[ct] = __builtin_amdgcn_mfma_f32_16x16x32_bf16(a, bfr, acc[ct], 0, 0, 0);
        }
    }

    // ---- softmax in-register; normalization deferred to output ----
    v4f rinv;
    {
        v4f mx4;
#pragma unroll
        for (int r = 0; r < 4; ++r)
            mx4[r] = fmaxf(fmaxf(acc[0][r], acc[1][r]), fmaxf(acc[2][r], acc[3][r]));
#pragma unroll
        for (int off = 1; off < 16; off <<= 1)
#pragma unroll
            for (int r = 0; r < 4; ++r)
                mx4[r] = fmaxf(mx4[r], __shfl_xor(mx4[r], off));
        v4f s4 = {0.f, 0.f, 0.f, 0.f};
#pragma unroll
        for (int ct = 0; ct < 4; ++ct)
#pragma unroll
            for (int r = 0; r < 4; ++r) {
                acc[ct][r] = __expf((acc[ct][r] - mx4[r]) * SCALE);
                s4[r] += acc[ct][r];
            }
#pragma unroll
        for (int off = 1; off < 16; off <<= 1)
#pragma unroll
            for (int r = 0; r < 4; ++r)
                s4[r] += __shfl_xor(s4[r], off);
#pragma unroll
        for (int r = 0; r < 4; ++r) rinv[r] = 1.f / s4[r];
        // write unnormalized P (bf16); wave-private rows -> no barrier
#pragma unroll
        for (int ct = 0; ct < 4; ++ct)
#pragma unroll
            for (int r = 0; r < 4; ++r)
                pt[(rowbase + lg * 4 + r) * PTS + ct * 16 + lw] = bf1(acc[ct][r]);
    }

    // ---- O = (P V) * rinv ----
    {
        v8s pa[2];
#pragma unroll
        for (int kt = 0; kt < 2; ++kt)
            pa[kt] = *(const v8s*)&pt[(rowbase + lw) * PTS + kt * 32 + lg * 8];
        v4f acc2[2] = {};
#pragma unroll
        for (int dt = 0; dt < 2; ++dt)
#pragma unroll
            for (int kt = 0; kt < 2; ++kt) {
                v8s vb = *(const v8s*)&vt[(dt * 16 + lw) * VTS + kt * 32 + lg * 8];
                acc2[dt] = __builtin_amdgcn_mfma_f32_16x16x32_bf16(pa[kt], vb, acc2[dt], 0, 0, 0);
            }
#pragma unroll
        for (int dt = 0; dt < 2; ++dt)
#pragma unroll
            for (int r = 0; r < 4; ++r) {
                int n = rowbase + lg * 4 + r;
                size_t off = (((size_t)b * IMG + bh * 8 + (n >> 3)) * IMG
                              + (bw * 8 + (n & 7))) * CDIM + head * HD + dt * 16 + lw;
                out[off] = acc2[dt][r] * rinv[r];
            }
    }
}

extern "C" void kernel_launch(void* const* d_in, const int* in_sizes, int n_in,
                              void* d_out, int out_size, void* d_ws, size_t ws_size,
                              hipStream_t stream) {
    const float* qkv = (const float*)d_in[0];
    const float* wp  = (const float*)d_in[1];
    const float* bp  = (const float*)d_in[2];
    const float* g1  = (const float*)d_in[3];
    const float* be1 = (const float*)d_in[4];
    const float* w1  = (const float*)d_in[5];
    const float* b1  = (const float*)d_in[6];
    const float* g2  = (const float*)d_in[7];
    const float* be2 = (const float*)d_in[8];
    const float* w2  = (const float*)d_in[9];
    const float* b2  = (const float*)d_in[10];
    const float* g3  = (const float*)d_in[11];
    const float* be3 = (const float*)d_in[12];
    const float* w3  = (const float*)d_in[13];
    const float* b3  = (const float*)d_in[14];

    float* rpb = (float*)d_ws;  // 6*64*64 floats (pre-divided by SCALE)
    posbias_kernel<<<96, 256, 0, stream>>>(wp, bp, g1, be1, w1, b1,
                                           g2, be2, w2, b2, g3, be3, w3, b3, rpb);
    win_attn_mfma<<<NWIN * NHEADS, 256, 0, stream>>>(qkv, rpb, (float*)d_out);
}

// Round 6
// 97.878 us; speedup vs baseline: 1.1497x; 1.0140x over previous
//
#include <hip/hip_runtime.h>
#include <hip/hip_bf16.h>

#define NHEADS 6
#define HD 32
#define CDIM 192
#define NTOK 64
#define NREL 225
#define PDIM 12
#define IMG 256
#define NWW 32
#define NWIN 2048
#define SCALE 0.17677669529663687f
#define INV_SCALE 5.656854249492381f

typedef __attribute__((ext_vector_type(8))) short v8s;
typedef __attribute__((ext_vector_type(4))) float v4f;

#define QKS 40   // ks row stride (ushort) = 80B
#define VTS 72   // vt row stride = 144B
#define PTS 72   // pt row stride = 144B

__device__ __forceinline__ unsigned pkbf(float x, float y) {
    __hip_bfloat162 h = __float22bfloat162_rn(make_float2(x, y));
    union { __hip_bfloat162 h; unsigned u; } c; c.h = h;
    return c.u;
}
__device__ __forceinline__ unsigned short bf1(float x) {
    __hip_bfloat16 h = __float2bfloat16(x);
    union { __hip_bfloat16 h; unsigned short u; } c; c.h = h;
    return c.u;
}

__device__ __forceinline__ void ln_relu12(const float* x, const float* g,
                                          const float* be, float* y) {
    float m = 0.f;
#pragma unroll
    for (int i = 0; i < PDIM; ++i) m += x[i];
    m *= (1.f / PDIM);
    float v = 0.f;
#pragma unroll
    for (int i = 0; i < PDIM; ++i) { float d = x[i] - m; v += d * d; }
    v *= (1.f / PDIM);
    float inv = rsqrtf(v + 1e-5f);
#pragma unroll
    for (int i = 0; i < PDIM; ++i) {
        float t = (x[i] - m) * inv * g[i] + be[i];
        y[i] = t > 0.f ? t : 0.f;
    }
}

// 1 block: compact 225x6 table, pre-multiplied by 1/SCALE, head-major layout
__global__ __launch_bounds__(256) void posbias_kernel(
    const float* __restrict__ wp, const float* __restrict__ bp,
    const float* __restrict__ g1, const float* __restrict__ be1,
    const float* __restrict__ w1, const float* __restrict__ b1,
    const float* __restrict__ g2, const float* __restrict__ be2,
    const float* __restrict__ w2, const float* __restrict__ b2,
    const float* __restrict__ g3, const float* __restrict__ be3,
    const float* __restrict__ w3, const float* __restrict__ b3,
    float* __restrict__ p_t)
{
    int r = threadIdx.x;
    if (r >= NREL) return;
    float x0 = (float)(r / 15 - 7);
    float x1 = (float)(r % 15 - 7);
    float h[PDIM], y[PDIM];
#pragma unroll
    for (int o = 0; o < PDIM; ++o)
        h[o] = x0 * wp[o] + x1 * wp[PDIM + o] + bp[o];
    ln_relu12(h, g1, be1, y);
#pragma unroll
    for (int o = 0; o < PDIM; ++o) {
        float a = b1[o];
#pragma unroll
        for (int i = 0; i < PDIM; ++i) a += y[i] * w1[i * PDIM + o];
        h[o] = a;
    }
    ln_relu12(h, g2, be2, y);
#pragma unroll
    for (int o = 0; o < PDIM; ++o) {
        float a = b2[o];
#pragma unroll
        for (int i = 0; i < PDIM; ++i) a += y[i] * w2[i * PDIM + o];
        h[o] = a;
    }
    ln_relu12(h, g3, be3, y);
#pragma unroll
    for (int o = 0; o < NHEADS; ++o) {
        float a = b3[o];
#pragma unroll
        for (int i = 0; i < PDIM; ++i) a += y[i] * w3[i * NHEADS + o];
        p_t[o * NREL + r] = a * INV_SCALE;
    }
}

__global__ __launch_bounds__(256) void win_attn_mfma(
    const float* __restrict__ qkv, const float* __restrict__ p_t,
    float* __restrict__ out)
{
    __shared__ unsigned short ks[NTOK * QKS];  // K row-major bf16
    __shared__ unsigned short vt[HD * VTS];    // V transposed bf16
    __shared__ unsigned short pt[NTOK * PTS];  // P bf16 (wave-private rows)
    __shared__ float psh[NREL];                // compact bias for this head

    const int t = threadIdx.x;
    const int head = blockIdx.x >> 11;
    const int win  = blockIdx.x & (NWIN - 1);
    const int b    = win >> 10;
    const int bh   = (win >> 5) & 31;
    const int bw   = win & 31;

    const int lane = t & 63;
    const int wave = t >> 6;
    const int lw = lane & 15;
    const int lg = lane >> 4;
    const int rowbase = wave * 16;

    const size_t SST = (size_t)2 * IMG * IMG * CDIM;
    const float* basep = qkv + (size_t)b * IMG * IMG * CDIM + head * HD;

    auto toff = [&](int tok) -> size_t {
        return ((size_t)(bh * 8 + (tok >> 3)) * IMG + (bw * 8 + (tok & 7))) * CDIM;
    };

    // ---- compact bias table into LDS (1 load for 225 threads) ----
    if (t < NREL) psh[t] = p_t[head * NREL + t];

    // ---- stage K (row-major) + V (transposed) ----
#pragma unroll
    for (int pass = 0; pass < 2; ++pass) {
        int idx = t + pass * 256;
        int tok = idx >> 3;
        int d   = (idx & 7) * 4;
        const float* kp = basep + SST + toff(tok) + d;
        float4 k4 = *(const float4*)kp;
        float4 v4 = *(const float4*)(kp + SST);
        uint2 kk; kk.x = pkbf(k4.x, k4.y); kk.y = pkbf(k4.z, k4.w);
        *(uint2*)&ks[tok * QKS + d] = kk;
        vt[(d + 0) * VTS + tok] = bf1(v4.x);
        vt[(d + 1) * VTS + tok] = bf1(v4.y);
        vt[(d + 2) * VTS + tok] = bf1(v4.z);
        vt[(d + 3) * VTS + tok] = bf1(v4.w);
    }

    // ---- Q A-fragment direct from global ----
    v8s a;
    {
        const float* qp = basep + toff(rowbase + lw) + lg * 8;
        float4 q0 = *(const float4*)qp;
        float4 q1 = *(const float4*)(qp + 4);
        union { v8s v; unsigned u[4]; } au;
        au.u[0] = pkbf(q0.x, q0.y);
        au.u[1] = pkbf(q0.z, q0.w);
        au.u[2] = pkbf(q1.x, q1.y);
        au.u[3] = pkbf(q1.z, q1.w);
        a = au.v;
    }
    __syncthreads();   // ks, vt, psh visible

    // ---- S' = Q K^T (C = 0) ----
    v4f acc[4];
#pragma unroll
    for (int ct = 0; ct < 4; ++ct) {
        v4f z = {0.f, 0.f, 0.f, 0.f};
        v8s bfr = *(const v8s*)&ks[(ct * 16 + lw) * QKS + lg * 8];
        acc[ct] = __builtin_amdgcn_mfma_f32_16x16x32_bf16(a, bfr, z, 0, 0, 0);
    }

    // ---- bias add (LDS gather) + exp (no max-sub) + row sum ----
    v4f rinv;
    {
        int base_r[4];
#pragma unroll
        for (int r = 0; r < 4; ++r) {
            int n = rowbase + lg * 4 + r;
            base_r[r] = ((n >> 3) - (lw >> 3) + 7) * 15 + (n & 7) - (lw & 7) + 7;
        }
        v4f s4 = {0.f, 0.f, 0.f, 0.f};
#pragma unroll
        for (int ct = 0; ct < 4; ++ct)
#pragma unroll
            for (int r = 0; r < 4; ++r) {
                float e = __expf((acc[ct][r] + psh[base_r[r] - ct * 30]) * SCALE);
                acc[ct][r] = e;
                s4[r] += e;
            }
#pragma unroll
        for (int off = 1; off < 16; off <<= 1)
#pragma unroll
            for (int r = 0; r < 4; ++r)
                s4[r] += __shfl_xor(s4[r], off);
#pragma unroll
        for (int r = 0; r < 4; ++r) rinv[r] = __builtin_amdgcn_rcpf(s4[r]);
        // unnormalized P (bf16); wave-private rows -> no barrier needed
#pragma unroll
        for (int ct = 0; ct < 4; ++ct)
#pragma unroll
            for (int r = 0; r < 4; ++r)
                pt[(rowbase + lg * 4 + r) * PTS + ct * 16 + lw] = bf1(acc[ct][r]);
    }

    // ---- O = (P V) * rinv ----
    {
        v8s pa[2];
#pragma unroll
        for (int kt = 0; kt < 2; ++kt)
            pa[kt] = *(const v8s*)&pt[(rowbase + lw) * PTS + kt * 32 + lg * 8];
        v4f acc2[2] = {};
#pragma unroll
        for (int dt = 0; dt < 2; ++dt)
#pragma unroll
            for (int kt = 0; kt < 2; ++kt) {
                v8s vb = *(const v8s*)&vt[(dt * 16 + lw) * VTS + kt * 32 + lg * 8];
                acc2[dt] = __builtin_amdgcn_mfma_f32_16x16x32_bf16(pa[kt], vb, acc2[dt], 0, 0, 0);
            }
#pragma unroll
        for (int dt = 0; dt < 2; ++dt)
#pragma unroll
            for (int r = 0; r < 4; ++r) {
                int n = rowbase + lg * 4 + r;
                size_t off = (((size_t)b * IMG + bh * 8 + (n >> 3)) * IMG
                              + (bw * 8 + (n & 7))) * CDIM + head * HD + dt * 16 + lw;
                out[off] = acc2[dt][r] * rinv[r];
            }
    }
}

extern "C" void kernel_launch(void* const* d_in, const int* in_sizes, int n_in,
                              void* d_out, int out_size, void* d_ws, size_t ws_size,
                              hipStream_t stream) {
    const float* qkv = (const float*)d_in[0];
    const float* wp  = (const float*)d_in[1];
    const float* bp  = (const float*)d_in[2];
    const float* g1  = (const float*)d_in[3];
    const float* be1 = (const float*)d_in[4];
    const float* w1  = (const float*)d_in[5];
    const float* b1  = (const float*)d_in[6];
    const float* g2  = (const float*)d_in[7];
    const float* be2 = (const float*)d_in[8];
    const float* w2  = (const float*)d_in[9];
    const float* b2  = (const float*)d_in[10];
    const float* g3  = (const float*)d_in[11];
    const float* be3 = (const float*)d_in[12];
    const float* w3  = (const float*)d_in[13];
    const float* b3  = (const float*)d_in[14];

    float* p_t = (float*)d_ws;  // 6*225 floats (head-major, pre-scaled)
    posbias_kernel<<<1, 256, 0, stream>>>(wp, bp, g1, be1, w1, b1,
                                          g2, be2, w2, b2, g3, be3, w3, b3, p_t);
    win_attn_mfma<<<NWIN * NHEADS, 256, 0, stream>>>(qkv, p_t, (float*)d_out);
}